// Round 16
// baseline (2331.870 us; speedup 1.0000x reference)
//
#include <hip/hip_runtime.h>

#define NN_ 8192
#define MM_ 1024
#define NROWS_ 262144  // 8 * 1024 * 32 rows through the MLP

// DPP wave64 reduce steps on packed u64 keys (pure VALU, no LDS pipe).
#define DPP_UMAX64(K, CTRL)                                                     \
  {                                                                             \
    const int lo_ = (int)(unsigned int)(K);                                     \
    const int hi_ = (int)(unsigned int)((K) >> 32);                             \
    const int slo_ = __builtin_amdgcn_update_dpp(lo_, lo_, (CTRL), 0xf, 0xf, false); \
    const int shi_ = __builtin_amdgcn_update_dpp(hi_, hi_, (CTRL), 0xf, 0xf, false); \
    const unsigned long long ok_ =                                              \
        ((unsigned long long)(unsigned int)shi_ << 32) | (unsigned int)slo_;    \
    (K) = (ok_ > (K)) ? ok_ : (K);                                              \
  }
#define DPP_UMIN64(K, CTRL)                                                     \
  {                                                                             \
    const int lo_ = (int)(unsigned int)(K);                                     \
    const int hi_ = (int)(unsigned int)((K) >> 32);                             \
    const int slo_ = __builtin_amdgcn_update_dpp(lo_, lo_, (CTRL), 0xf, 0xf, false); \
    const int shi_ = __builtin_amdgcn_update_dpp(hi_, hi_, (CTRL), 0xf, 0xf, false); \
    const unsigned long long ok_ =                                              \
        ((unsigned long long)(unsigned int)shi_ << 32) | (unsigned int)slo_;    \
    (K) = (ok_ < (K)) ? ok_ : (K);                                              \
  }

// Per-wave channel-stats via rotated LDS transpose (conflict-free both ways).
#define WAVE_STATS(T, ACC, PO_S, PO_Q)                                          \
  {                                                                             \
    _Pragma("unroll") for (int o_ = 0; o_ < 64; ++o_)                           \
        (T)[o_ * 64 + ((lane + o_) & 63)] = (ACC)[o_];                          \
    float s_ = 0.0f, q_ = 0.0f;                                                 \
    _Pragma("unroll") for (int j_ = 0; j_ < 64; ++j_) {                         \
      const float v_ = (T)[lane * 64 + ((j_ + lane) & 63)];                     \
      s_ += v_;                                                                 \
      q_ = fmaf(v_, v_, q_);                                                    \
    }                                                                           \
    (PO_S)[lane] = s_;                                                          \
    (PO_Q)[lane] = q_;                                                          \
  }

// ============ last-block BN-stat reduction (threadFenceReduction pattern) ====
// All blocks: device fence + ticket. The last block reduces the partials in a
// FIXED order (deterministic regardless of which block is last) and writes
// the folded scale/shift. cnt is zeroed by hipMemsetAsync each launch.
__device__ __forceinline__ void lastblock_rstat(const float* part, int C, int rows,
                                                const float* g, const float* be,
                                                float* sc, float* sh,
                                                unsigned* cnt, int nblocks, int tid) {
  __threadfence();   // release this block's partial writes (device scope)
  __syncthreads();
  __shared__ int amLast;
  if (tid == 0) {
    const unsigned t = atomicAdd(cnt, 1u);
    amLast = (t == (unsigned)(nblocks - 1));
  }
  __syncthreads();
  if (!amLast) return;
  __threadfence();   // acquire: see all blocks' partials
  const int c = tid % C;           // C = 64 -> 4 strips; C = 128 -> 2 strips
  const int strip = tid / C;
  const int nstrips = 256 / C;
  const int per = rows / nstrips;
  float S = 0.0f, Q = 0.0f;
  for (int i = strip * per; i < (strip + 1) * per; ++i) {
    S += part[(size_t)i * 2 * C + c];
    Q += part[(size_t)i * 2 * C + C + c];
  }
  __shared__ float rs[256], rq[256];
  rs[tid] = S;
  rq[tid] = Q;
  __syncthreads();
  if (tid < C) {
    float Ss = rs[tid], Qs = rq[tid];
    for (int s2 = 1; s2 < nstrips; ++s2) { Ss += rs[s2 * C + tid]; Qs += rq[s2 * C + tid]; }
    const float mean = Ss * (1.0f / 262144.0f);
    const float var = fmaf(-mean, mean, Qs * (1.0f / 262144.0f));
    const float s = g[tid] * rsqrtf(var + 1e-5f);
    sc[tid] = s;
    sh[tid] = fmaf(-mean, s, be[tid]);
  }
}

// ============================ FPS =============================
// EXACT R7/R13 inner loop (best measured: 898 us). NEW: former prep_kernel
// (weight transposes) folded into the head — 8x256 threads grid-stride the
// 12288 elements; consumers (chain kernels) run much later.
__global__ __launch_bounds__(256, 1) void fps_kernel(const float* __restrict__ xyz,
                                                     float* __restrict__ dout,
                                                     const float* __restrict__ w1,
                                                     const float* __restrict__ w2,
                                                     float* __restrict__ w1t,
                                                     float* __restrict__ w2t) {
  const int b = blockIdx.x;
  const int tid = threadIdx.x;
  const float* xb = xyz + (size_t)b * NN_ * 3;

  // folded prep: fill w1t (4096) and w2t (8192)
  for (int i = b * 256 + tid; i < 12288; i += 2048) {
    if (i < 4096) {
      const int o = i >> 6, c = i & 63;
      w1t[c * 64 + o] = w1[i];
    } else {
      const int j = i - 4096;
      const int o = j >> 6, c = j & 63;
      w2t[c * 128 + o] = w2[j];
    }
  }

  __shared__ float s_x[NN_], s_y[NN_], s_z[NN_];          // 96 KB SoA coords
  __shared__ float s_out[3 * MM_];                        // 12 KB centroids
  __shared__ __align__(16) unsigned long long s_key[2][4];  // [parity][wave]

  for (int i = tid; i < NN_; i += 256) {
    s_x[i] = xb[3 * i + 0];
    s_y[i] = xb[3 * i + 1];
    s_z[i] = xb[3 * i + 2];
  }
  __syncthreads();

  // 32 owned points -> registers (8 float4 per axis)
  const int base = 32 * tid;
  float4 rx[8], ry[8], rz[8];
#pragma unroll
  for (int q = 0; q < 8; ++q) {
    rx[q] = *(const float4*)&s_x[base + 4 * q];
    ry[q] = *(const float4*)&s_y[base + 4 * q];
    rz[q] = *(const float4*)&s_z[base + 4 * q];
  }
  // Compiler barrier: LDS must be assumed modified after this point, so the
  // loads above cannot be sunk/remat'ed into the loop. Values stay in VGPRs.
  asm volatile("" ::: "memory");

  float pd[32];
#pragma unroll
  for (int j = 0; j < 32; ++j) pd[j] = 1e10f;

  const int lane = tid & 63;
  const int wv = tid >> 6;

  float cx = s_x[0], cy = s_y[0], cz = s_z[0];  // exact copies of xb[0..2]

  for (int it = 0; it < MM_; ++it) {
    if (tid == 0) {
      s_out[it * 3 + 0] = cx;
      s_out[it * 3 + 1] = cy;
      s_out[it * 3 + 2] = cz;
    }
    if (it == MM_ - 1) break;

    // ---- distance update + serial ascending-j argmax over 32 reg points ----
    float ld = -1.0f;
    int lj = 0;
#define FPS_UPD(PX, PY, PZ, J)                                                 \
    {                                                                          \
      const float dx = __fsub_rn(PX, cx);                                      \
      const float dy = __fsub_rn(PY, cy);                                      \
      const float dz = __fsub_rn(PZ, cz);                                      \
      const float dist = __fadd_rn(                                            \
          __fadd_rn(__fmul_rn(dx, dx), __fmul_rn(dy, dy)), __fmul_rn(dz, dz)); \
      const float nd = fminf(pd[J], dist);                                     \
      pd[J] = nd;                                                              \
      if (nd > ld) { ld = nd; lj = (J); }                                      \
    }
#pragma unroll
    for (int q = 0; q < 8; ++q) {
      FPS_UPD(rx[q].x, ry[q].x, rz[q].x, 4 * q + 0)
      FPS_UPD(rx[q].y, ry[q].y, rz[q].y, 4 * q + 1)
      FPS_UPD(rx[q].z, ry[q].z, rz[q].z, 4 * q + 2)
      FPS_UPD(rx[q].w, ry[q].w, rz[q].w, 4 * q + 3)
    }
#undef FPS_UPD

    // monotone packed key: max dist, tie -> smaller p (p = base + lj)
    unsigned long long key =
        ((unsigned long long)__float_as_uint(ld) << 32) |
        (unsigned int)(8191 - (base + lj));
    DPP_UMAX64(key, 0x111)
    DPP_UMAX64(key, 0x112)
    DPP_UMAX64(key, 0x114)
    DPP_UMAX64(key, 0x118)
    DPP_UMAX64(key, 0x142)
    DPP_UMAX64(key, 0x143)
    if (lane == 63) s_key[it & 1][wv] = key;
    __syncthreads();

    // cross-wave: 2x b128 reads + 3 u64 selects (redundant per thread)
    const ulonglong2 ka = *(const ulonglong2*)&s_key[it & 1][0];
    const ulonglong2 kb = *(const ulonglong2*)&s_key[it & 1][2];
    unsigned long long best = (ka.x > ka.y) ? ka.x : ka.y;
    const unsigned long long bb = (kb.x > kb.y) ? kb.x : kb.y;
    best = (best > bb) ? best : bb;
    const int win = 8191 - (int)(unsigned int)(best & 0xFFFFFFFFu);
    // new centroid: exact coords via broadcast LDS reads
    cx = s_x[win];
    cy = s_y[win];
    cz = s_z[win];
  }

  __syncthreads();
  float* outx = dout + (size_t)b * MM_ * 3;
#pragma unroll
  for (int i = 0; i < 12; ++i) outx[i * 256 + tid] = s_out[i * 256 + tid];
}

// ============================ KNN =============================
// One wave per center; lane owns 128 points. Incremental local-best + DPP
// u64-min extraction with order-preserving float->u32 transform (handles
// negative decomposed distances). Tie -> smaller p (top_k stable order).
__global__ __launch_bounds__(64) void knn_kernel(const float* __restrict__ xyz,
                                                 const float* __restrict__ dout,
                                                 int* __restrict__ knn) {
  __shared__ float dl[128][64];
  const int lane = threadIdx.x;
  const int center = blockIdx.x;
  const int b = center >> 10;
  const int m = center & 1023;
  const float* xb = xyz + (size_t)b * NN_ * 3;
  const float* cp = dout + (size_t)b * MM_ * 3 + m * 3;
  const float cx = cp[0], cy = cp[1], cz = cp[2];
  const float sm = __fadd_rn(__fadd_rn(__fmul_rn(cx, cx), __fmul_rn(cy, cy)),
                             __fmul_rn(cz, cz));

  float gd[16];
  int gj[16];
#pragma unroll
  for (int g = 0; g < 16; ++g) {
#pragma unroll
    for (int t = 0; t < 8; ++t) {
      const int jj = g * 8 + t;
      const int p = jj * 64 + lane;
      const float x = xb[p * 3 + 0];
      const float y = xb[p * 3 + 1];
      const float z = xb[p * 3 + 2];
      const float sn = __fadd_rn(__fadd_rn(__fmul_rn(x, x), __fmul_rn(y, y)),
                                 __fmul_rn(z, z));
      // FMA-chained contraction (matches einsum inner loop)
      const float dt = __fmaf_rn(cz, z, __fmaf_rn(cy, y, __fmul_rn(cx, x)));
      const float d = __fsub_rn(__fadd_rn(sm, sn), __fmul_rn(2.0f, dt));
      dl[jj][lane] = d;
      if (t == 0) { gd[g] = d; gj[g] = jj; }
      else if (d < gd[g]) { gd[g] = d; gj[g] = jj; }
    }
  }

  // one-time local best + packed key (order-preserving float->u32 map)
  float ldv = gd[0];
  int ljj = gj[0];
#pragma unroll
  for (int g = 1; g < 16; ++g) {
    if (gd[g] < ldv) { ldv = gd[g]; ljj = gj[g]; }
  }
  unsigned db = __float_as_uint(ldv);
  unsigned mono = (db & 0x80000000u) ? ~db : (db | 0x80000000u);
  unsigned long long mykey =
      ((unsigned long long)mono << 32) | (unsigned int)(ljj * 64 + lane);

  int out_p = 0;
  const float INF = __int_as_float(0x7f800000);
  for (int r = 0; r < 32; ++r) {
    unsigned long long kk = mykey;
    DPP_UMIN64(kk, 0x111)
    DPP_UMIN64(kk, 0x112)
    DPP_UMIN64(kk, 0x114)
    DPP_UMIN64(kk, 0x118)
    DPP_UMIN64(kk, 0x142)
    DPP_UMIN64(kk, 0x143)
    const int lp = __builtin_amdgcn_readlane((int)(unsigned int)(kk & 0xFFFFFFFFull), 63);
    if (lane == r) out_p = lp;
    // winner lane: mark slot, rebuild its group min, re-scan, repack key
    const int wl = lp & 63;
    if (lane == wl) {
      const int jjs = lp >> 6;
      const int gs = jjs >> 3;
      dl[jjs][lane] = INF;
      float md = INF;
      int mj = 0;
#pragma unroll
      for (int t = 0; t < 8; ++t) {
        const int jj2 = gs * 8 + t;
        const float v = dl[jj2][lane];
        if (v < md) { md = v; mj = jj2; }
      }
#pragma unroll
      for (int g = 0; g < 16; ++g) {
        if (g == gs) { gd[g] = md; gj[g] = mj; }
      }
      float nldv = gd[0];
      int nljj = gj[0];
#pragma unroll
      for (int g = 1; g < 16; ++g) {
        if (gd[g] < nldv) { nldv = gd[g]; nljj = gj[g]; }
      }
      const unsigned ndb = __float_as_uint(nldv);
      const unsigned nmono = (ndb & 0x80000000u) ? ~ndb : (ndb | 0x80000000u);
      mykey = ((unsigned long long)nmono << 32) |
              (unsigned int)(nljj * 64 + lane);
    }
  }
  if (lane < 32) knn[center * 32 + lane] = out_p;
}

// ===================== layer-1 stats pass (+ fused rstat1) =====================
__global__ __launch_bounds__(256) void s1_kernel(const float* __restrict__ xyz,
                                                 const float* __restrict__ dout,
                                                 const int* __restrict__ knn,
                                                 const float* __restrict__ w0,
                                                 const float* __restrict__ b0,
                                                 float* __restrict__ part1,
                                                 const float* __restrict__ g0,
                                                 const float* __restrict__ be0,
                                                 float* __restrict__ sc1,
                                                 float* __restrict__ sh1,
                                                 unsigned* __restrict__ cnt) {
  __shared__ float tw[4 * 4096];  // 64 KB transpose buffers (16 KB/wave)
  const int tid = threadIdx.x;
  const int r = blockIdx.x * 256 + tid;
  const int cid = r >> 5;
  const int b = cid >> 10;
  const int m = cid & 1023;
  const int idx = knn[r];
  const float* pp = xyz + ((size_t)b * NN_ + idx) * 3;
  const float* cc = dout + ((size_t)b * MM_ + m) * 3;
  const float fx = pp[0] - cc[0];
  const float fy = pp[1] - cc[1];
  const float fz = pp[2] - cc[2];
  float acc[64];
#pragma unroll
  for (int o = 0; o < 64; ++o)
    acc[o] = fmaf(w0[o * 3 + 2], fz, fmaf(w0[o * 3 + 1], fy, fmaf(w0[o * 3 + 0], fx, b0[o])));
  const int lane = tid & 63;
  const int wv = tid >> 6;
  float* T = &tw[wv * 4096];
  float* po = part1 + ((size_t)blockIdx.x * 4 + wv) * 128;
  WAVE_STATS(T, acc, po, po + 64)
  lastblock_rstat(part1, 64, 4096, g0, be0, sc1, sh1, cnt, 1024, tid);
}

// ============ recompute chain: STAGE 2 = stats2, 3 = stats3, 4 = final ============
// ws-gated a2 caching (bit-identical reload path). STAGE 2/3 fuse their BN
// reduction via lastblock_rstat (no separate rstat kernels).
template <int STAGE>
__global__ __launch_bounds__(256) void chain_kernel(
    const float* __restrict__ xyz, const float* __restrict__ dout,
    const int* __restrict__ knn,
    const float* __restrict__ w0, const float* __restrict__ b0,
    const float* __restrict__ w1t, const float* __restrict__ b1,
    const float* __restrict__ w2t, const float* __restrict__ b2,
    const float* __restrict__ sc1, const float* __restrict__ sh1,
    const float* __restrict__ sc2, const float* __restrict__ sh2,
    const float* __restrict__ sc3, const float* __restrict__ sh3,
    float* __restrict__ part, float* __restrict__ outp,
    float* __restrict__ a2g, int cached,
    const float* __restrict__ gN, const float* __restrict__ beN,
    float* __restrict__ scw, float* __restrict__ shw,
    unsigned* __restrict__ cnt) {
  __shared__ float f[64 * 256];  // activations, column layout [c][tid]
  const int tid = threadIdx.x;
  const int r = blockIdx.x * 256 + tid;
  const int cid = r >> 5;
  const int b = cid >> 10;
  const int m = cid & 1023;
  const int lane = tid & 63;
  const int wv = tid >> 6;

  float a2[64];
  if (STAGE == 2 || !cached) {
    const int idx = knn[r];
    const float* pp = xyz + ((size_t)b * NN_ + idx) * 3;
    const float* cc = dout + ((size_t)b * MM_ + m) * 3;
    const float fx = pp[0] - cc[0];
    const float fy = pp[1] - cc[1];
    const float fz = pp[2] - cc[2];
    float acc[64];
#pragma unroll
    for (int o = 0; o < 64; ++o)
      acc[o] = fmaf(w0[o * 3 + 2], fz, fmaf(w0[o * 3 + 1], fy, fmaf(w0[o * 3 + 0], fx, b0[o])));
    // BN1 + ReLU -> own column
#pragma unroll
    for (int o = 0; o < 64; ++o)
      f[o * 256 + tid] = fmaxf(fmaf(acc[o], sc1[o], sh1[o]), 0.0f);
    // conv2 (output-stationary, uniform weight loads, own-column reads)
#pragma unroll
    for (int o = 0; o < 64; ++o) a2[o] = b1[o];
#pragma unroll 4
    for (int c = 0; c < 64; ++c) {
      const float x = f[c * 256 + tid];
#pragma unroll
      for (int o = 0; o < 64; ++o) a2[o] = fmaf(w1t[c * 64 + o], x, a2[o]);
    }
  } else {
    // cached path: reload bit-identical pre-BN conv2 output (coalesced)
#pragma unroll
    for (int o = 0; o < 64; ++o) a2[o] = a2g[(size_t)o * NROWS_ + r];
  }

  if constexpr (STAGE == 2) {
    if (cached) {
#pragma unroll
      for (int o = 0; o < 64; ++o) a2g[(size_t)o * NROWS_ + r] = a2[o];
    }
    __syncthreads();  // all conv2 column-reads done before overwriting f
    float* T = &f[wv * 4096];
    float* po = part + ((size_t)blockIdx.x * 4 + wv) * 128;
    WAVE_STATS(T, a2, po, po + 64)
    lastblock_rstat(part, 64, 4096, gN, beN, scw, shw, cnt, 1024, tid);
    return;
  }
  // BN2 + ReLU -> own column
#pragma unroll
  for (int o = 0; o < 64; ++o)
    f[o * 256 + tid] = fmaxf(fmaf(a2[o], sc2[o], sh2[o]), 0.0f);
  if constexpr (STAGE == 3) {
    // fused both-halves conv3, then transpose-stats twice
    float a3l[64], a3h[64];
#pragma unroll
    for (int o = 0; o < 64; ++o) { a3l[o] = b2[o]; a3h[o] = b2[64 + o]; }
#pragma unroll 2
    for (int c = 0; c < 64; ++c) {
      const float x = f[c * 256 + tid];
#pragma unroll
      for (int o = 0; o < 64; ++o) a3l[o] = fmaf(w2t[c * 128 + o], x, a3l[o]);
#pragma unroll
      for (int o = 0; o < 64; ++o) a3h[o] = fmaf(w2t[c * 128 + 64 + o], x, a3h[o]);
    }
    __syncthreads();  // all conv3 column-reads done before overwriting f
    float* T = &f[wv * 4096];
    float* po = part + ((size_t)blockIdx.x * 4 + wv) * 256;
    WAVE_STATS(T, a3l, po, po + 128)
    WAVE_STATS(T, a3h, po + 64, po + 192)
    lastblock_rstat(part, 128, 4096, gN, beN, scw, shw, cnt, 1024, tid);
    return;
  }
  // STAGE 4: conv3 + BN3 + ReLU + max over k + transposed store
#pragma unroll
  for (int h = 0; h < 2; ++h) {
    float a3[64];
#pragma unroll
    for (int o = 0; o < 64; ++o) a3[o] = b2[h * 64 + o];
#pragma unroll 4
    for (int c = 0; c < 64; ++c) {
      const float x = f[c * 256 + tid];
#pragma unroll
      for (int o = 0; o < 64; ++o) a3[o] = fmaf(w2t[c * 128 + h * 64 + o], x, a3[o]);
    }
#pragma unroll
    for (int o = 0; o < 64; ++o) {
      float v = fmaxf(fmaf(a3[o], sc3[h * 64 + o], sh3[h * 64 + o]), 0.0f);
#pragma unroll
      for (int mk = 1; mk < 32; mk <<= 1) v = fmaxf(v, __shfl_xor(v, mk, 64));
      if ((lane & 31) == 0)
        outp[24576 + (size_t)b * 131072 + (size_t)(h * 64 + o) * 1024 + m] = v;
    }
  }
}

// ============================ launch =============================
extern "C" void kernel_launch(void* const* d_in, const int* in_sizes, int n_in,
                              void* d_out, int out_size, void* d_ws, size_t ws_size,
                              hipStream_t stream) {
  const float* xyz = (const float*)d_in[0];
  const float* w0 = (const float*)d_in[1];
  const float* b0 = (const float*)d_in[2];
  const float* g0 = (const float*)d_in[3];
  const float* be0 = (const float*)d_in[4];
  const float* w1 = (const float*)d_in[5];
  const float* b1 = (const float*)d_in[6];
  const float* g1 = (const float*)d_in[7];
  const float* be1 = (const float*)d_in[8];
  const float* w2 = (const float*)d_in[9];
  const float* b2 = (const float*)d_in[10];
  const float* g2 = (const float*)d_in[11];
  const float* be2 = (const float*)d_in[12];
  float* out = (float*)d_out;
  char* ws = (char*)d_ws;

  // ws layout: low 16 MB small buffers; a2 cache at +16 MB if available.
  int* knn = (int*)ws;                                   // [8192][32] ints
  float* part1 = (float*)(ws + (size_t)1 * (1 << 20));   // [4096][128]
  float* part2 = (float*)(ws + (size_t)3 * (1 << 20));   // [4096][128]
  float* part3 = (float*)(ws + (size_t)5 * (1 << 20));   // [4096][256]
  float* sc1 = (float*)(ws + (size_t)9 * (1 << 20));
  float* sh1 = sc1 + 64;
  float* sc2 = sh1 + 64;
  float* sh2 = sc2 + 64;
  float* sc3 = sh2 + 64;
  float* sh3 = sc3 + 128;
  float* w1t = sh3 + 128;
  float* w2t = w1t + 4096;
  unsigned* cnt = (unsigned*)(w2t + 8192);               // 3 tickets
  float* a2g = (float*)(ws + ((size_t)16 << 20));        // [64][262144] = 64 MB
  const int cached = (ws_size >= ((size_t)81 << 20)) ? 1 : 0;

  hipMemsetAsync(cnt, 0, 3 * sizeof(unsigned), stream);
  fps_kernel<<<8, 256, 0, stream>>>(xyz, out, w1, w2, w1t, w2t);
  knn_kernel<<<8192, 64, 0, stream>>>(xyz, out, knn);
  s1_kernel<<<1024, 256, 0, stream>>>(xyz, out, knn, w0, b0, part1,
                                      g0, be0, sc1, sh1, cnt + 0);
  chain_kernel<2><<<1024, 256, 0, stream>>>(xyz, out, knn, w0, b0, w1t, b1, w2t, b2,
                                            sc1, sh1, sc2, sh2, sc3, sh3, part2, out,
                                            a2g, cached, g1, be1, sc2, sh2, cnt + 1);
  chain_kernel<3><<<1024, 256, 0, stream>>>(xyz, out, knn, w0, b0, w1t, b1, w2t, b2,
                                            sc1, sh1, sc2, sh2, sc3, sh3, part3, out,
                                            a2g, cached, g2, be2, sc3, sh3, cnt + 2);
  chain_kernel<4><<<1024, 256, 0, stream>>>(xyz, out, knn, w0, b0, w1t, b1, w2t, b2,
                                            sc1, sh1, sc2, sh2, sc3, sh3, part3, out,
                                            a2g, cached, (const float*)nullptr,
                                            (const float*)nullptr, (float*)nullptr,
                                            (float*)nullptr, (unsigned*)nullptr);
}

// Round 17
// 1479.051 us; speedup vs baseline: 1.5766x; 1.5766x over previous
//
#include <hip/hip_runtime.h>

#define NN_ 8192
#define MM_ 1024
#define NROWS_ 262144  // 8 * 1024 * 32 rows through the MLP

// DPP wave64 reduce steps on packed u64 keys (pure VALU, no LDS pipe).
#define DPP_UMAX64(K, CTRL)                                                     \
  {                                                                             \
    const int lo_ = (int)(unsigned int)(K);                                     \
    const int hi_ = (int)(unsigned int)((K) >> 32);                             \
    const int slo_ = __builtin_amdgcn_update_dpp(lo_, lo_, (CTRL), 0xf, 0xf, false); \
    const int shi_ = __builtin_amdgcn_update_dpp(hi_, hi_, (CTRL), 0xf, 0xf, false); \
    const unsigned long long ok_ =                                              \
        ((unsigned long long)(unsigned int)shi_ << 32) | (unsigned int)slo_;    \
    (K) = (ok_ > (K)) ? ok_ : (K);                                              \
  }
#define DPP_UMIN64(K, CTRL)                                                     \
  {                                                                             \
    const int lo_ = (int)(unsigned int)(K);                                     \
    const int hi_ = (int)(unsigned int)((K) >> 32);                             \
    const int slo_ = __builtin_amdgcn_update_dpp(lo_, lo_, (CTRL), 0xf, 0xf, false); \
    const int shi_ = __builtin_amdgcn_update_dpp(hi_, hi_, (CTRL), 0xf, 0xf, false); \
    const unsigned long long ok_ =                                              \
        ((unsigned long long)(unsigned int)shi_ << 32) | (unsigned int)slo_;    \
    (K) = (ok_ < (K)) ? ok_ : (K);                                              \
  }

// Per-wave channel-stats via rotated LDS transpose (conflict-free both ways).
#define WAVE_STATS(T, ACC, PO_S, PO_Q)                                          \
  {                                                                             \
    _Pragma("unroll") for (int o_ = 0; o_ < 64; ++o_)                           \
        (T)[o_ * 64 + ((lane + o_) & 63)] = (ACC)[o_];                          \
    float s_ = 0.0f, q_ = 0.0f;                                                 \
    _Pragma("unroll") for (int j_ = 0; j_ < 64; ++j_) {                         \
      const float v_ = (T)[lane * 64 + ((j_ + lane) & 63)];                     \
      s_ += v_;                                                                 \
      q_ = fmaf(v_, v_, q_);                                                    \
    }                                                                           \
    (PO_S)[lane] = s_;                                                          \
    (PO_Q)[lane] = q_;                                                          \
  }

// ============================ FPS =============================
// EXACT R7/R13 variant (best measured: 898 us; serial argmax is the proven
// local optimum — tree/indep-max/pk/hybrid all regressed R9/R11/R12/R14).
__global__ __launch_bounds__(256, 1) void fps_kernel(const float* __restrict__ xyz,
                                                     float* __restrict__ dout) {
  const int b = blockIdx.x;
  const int tid = threadIdx.x;
  const float* xb = xyz + (size_t)b * NN_ * 3;

  __shared__ float s_x[NN_], s_y[NN_], s_z[NN_];          // 96 KB SoA coords
  __shared__ float s_out[3 * MM_];                        // 12 KB centroids
  __shared__ __align__(16) unsigned long long s_key[2][4];  // [parity][wave]

  for (int i = tid; i < NN_; i += 256) {
    s_x[i] = xb[3 * i + 0];
    s_y[i] = xb[3 * i + 1];
    s_z[i] = xb[3 * i + 2];
  }
  __syncthreads();

  // 32 owned points -> registers (8 float4 per axis)
  const int base = 32 * tid;
  float4 rx[8], ry[8], rz[8];
#pragma unroll
  for (int q = 0; q < 8; ++q) {
    rx[q] = *(const float4*)&s_x[base + 4 * q];
    ry[q] = *(const float4*)&s_y[base + 4 * q];
    rz[q] = *(const float4*)&s_z[base + 4 * q];
  }
  // Compiler barrier: LDS must be assumed modified after this point, so the
  // loads above cannot be sunk/remat'ed into the loop. Values stay in VGPRs.
  asm volatile("" ::: "memory");

  float pd[32];
#pragma unroll
  for (int j = 0; j < 32; ++j) pd[j] = 1e10f;

  const int lane = tid & 63;
  const int wv = tid >> 6;

  float cx = s_x[0], cy = s_y[0], cz = s_z[0];  // exact copies of xb[0..2]

  for (int it = 0; it < MM_; ++it) {
    if (tid == 0) {
      s_out[it * 3 + 0] = cx;
      s_out[it * 3 + 1] = cy;
      s_out[it * 3 + 2] = cz;
    }
    if (it == MM_ - 1) break;

    // ---- distance update + serial ascending-j argmax over 32 reg points ----
    float ld = -1.0f;
    int lj = 0;
#define FPS_UPD(PX, PY, PZ, J)                                                 \
    {                                                                          \
      const float dx = __fsub_rn(PX, cx);                                      \
      const float dy = __fsub_rn(PY, cy);                                      \
      const float dz = __fsub_rn(PZ, cz);                                      \
      const float dist = __fadd_rn(                                            \
          __fadd_rn(__fmul_rn(dx, dx), __fmul_rn(dy, dy)), __fmul_rn(dz, dz)); \
      const float nd = fminf(pd[J], dist);                                     \
      pd[J] = nd;                                                              \
      if (nd > ld) { ld = nd; lj = (J); }                                      \
    }
#pragma unroll
    for (int q = 0; q < 8; ++q) {
      FPS_UPD(rx[q].x, ry[q].x, rz[q].x, 4 * q + 0)
      FPS_UPD(rx[q].y, ry[q].y, rz[q].y, 4 * q + 1)
      FPS_UPD(rx[q].z, ry[q].z, rz[q].z, 4 * q + 2)
      FPS_UPD(rx[q].w, ry[q].w, rz[q].w, 4 * q + 3)
    }
#undef FPS_UPD

    // monotone packed key: max dist, tie -> smaller p (p = base + lj)
    unsigned long long key =
        ((unsigned long long)__float_as_uint(ld) << 32) |
        (unsigned int)(8191 - (base + lj));
    DPP_UMAX64(key, 0x111)
    DPP_UMAX64(key, 0x112)
    DPP_UMAX64(key, 0x114)
    DPP_UMAX64(key, 0x118)
    DPP_UMAX64(key, 0x142)
    DPP_UMAX64(key, 0x143)
    if (lane == 63) s_key[it & 1][wv] = key;
    __syncthreads();

    // cross-wave: 2x b128 reads + 3 u64 selects (redundant per thread)
    const ulonglong2 ka = *(const ulonglong2*)&s_key[it & 1][0];
    const ulonglong2 kb = *(const ulonglong2*)&s_key[it & 1][2];
    unsigned long long best = (ka.x > ka.y) ? ka.x : ka.y;
    const unsigned long long bb = (kb.x > kb.y) ? kb.x : kb.y;
    best = (best > bb) ? best : bb;
    const int win = 8191 - (int)(unsigned int)(best & 0xFFFFFFFFu);
    // new centroid: exact coords via broadcast LDS reads
    cx = s_x[win];
    cy = s_y[win];
    cz = s_z[win];
  }

  __syncthreads();
  float* outx = dout + (size_t)b * MM_ * 3;
#pragma unroll
  for (int i = 0; i < 12; ++i) outx[i * 256 + tid] = s_out[i * 256 + tid];
}

// ============================ KNN =============================
// One wave per center; lane owns 128 points. Incremental local-best — each
// lane's (ldv,ljj) and packed key computed ONCE before the loop; per round
// only the DPP u64-min reduce + winner-lane update run. Order-preserving
// float->u32 transform handles negative decomposed distances (R10 bug).
// Tie -> smaller p (top_k stable order).
__global__ __launch_bounds__(64) void knn_kernel(const float* __restrict__ xyz,
                                                 const float* __restrict__ dout,
                                                 int* __restrict__ knn) {
  __shared__ float dl[128][64];
  const int lane = threadIdx.x;
  const int center = blockIdx.x;
  const int b = center >> 10;
  const int m = center & 1023;
  const float* xb = xyz + (size_t)b * NN_ * 3;
  const float* cp = dout + (size_t)b * MM_ * 3 + m * 3;
  const float cx = cp[0], cy = cp[1], cz = cp[2];
  const float sm = __fadd_rn(__fadd_rn(__fmul_rn(cx, cx), __fmul_rn(cy, cy)),
                             __fmul_rn(cz, cz));

  float gd[16];
  int gj[16];
#pragma unroll
  for (int g = 0; g < 16; ++g) {
#pragma unroll
    for (int t = 0; t < 8; ++t) {
      const int jj = g * 8 + t;
      const int p = jj * 64 + lane;
      const float x = xb[p * 3 + 0];
      const float y = xb[p * 3 + 1];
      const float z = xb[p * 3 + 2];
      const float sn = __fadd_rn(__fadd_rn(__fmul_rn(x, x), __fmul_rn(y, y)),
                                 __fmul_rn(z, z));
      // FMA-chained contraction (matches einsum inner loop)
      const float dt = __fmaf_rn(cz, z, __fmaf_rn(cy, y, __fmul_rn(cx, x)));
      const float d = __fsub_rn(__fadd_rn(sm, sn), __fmul_rn(2.0f, dt));
      dl[jj][lane] = d;
      if (t == 0) { gd[g] = d; gj[g] = jj; }
      else if (d < gd[g]) { gd[g] = d; gj[g] = jj; }
    }
  }

  // one-time local best + packed key (order-preserving float->u32 map)
  float ldv = gd[0];
  int ljj = gj[0];
#pragma unroll
  for (int g = 1; g < 16; ++g) {
    if (gd[g] < ldv) { ldv = gd[g]; ljj = gj[g]; }
  }
  unsigned db = __float_as_uint(ldv);
  unsigned mono = (db & 0x80000000u) ? ~db : (db | 0x80000000u);
  unsigned long long mykey =
      ((unsigned long long)mono << 32) | (unsigned int)(ljj * 64 + lane);

  int out_p = 0;
  const float INF = __int_as_float(0x7f800000);
  for (int r = 0; r < 32; ++r) {
    unsigned long long kk = mykey;
    DPP_UMIN64(kk, 0x111)
    DPP_UMIN64(kk, 0x112)
    DPP_UMIN64(kk, 0x114)
    DPP_UMIN64(kk, 0x118)
    DPP_UMIN64(kk, 0x142)
    DPP_UMIN64(kk, 0x143)
    const int lp = __builtin_amdgcn_readlane((int)(unsigned int)(kk & 0xFFFFFFFFull), 63);
    if (lane == r) out_p = lp;
    // winner lane: mark slot, rebuild its group min, re-scan, repack key
    const int wl = lp & 63;
    if (lane == wl) {
      const int jjs = lp >> 6;
      const int gs = jjs >> 3;
      dl[jjs][lane] = INF;
      float md = INF;
      int mj = 0;
#pragma unroll
      for (int t = 0; t < 8; ++t) {
        const int jj2 = gs * 8 + t;
        const float v = dl[jj2][lane];
        if (v < md) { md = v; mj = jj2; }
      }
#pragma unroll
      for (int g = 0; g < 16; ++g) {
        if (g == gs) { gd[g] = md; gj[g] = mj; }
      }
      // recompute local best (only this lane's state changed)
      float nldv = gd[0];
      int nljj = gj[0];
#pragma unroll
      for (int g = 1; g < 16; ++g) {
        if (gd[g] < nldv) { nldv = gd[g]; nljj = gj[g]; }
      }
      const unsigned ndb = __float_as_uint(nldv);
      const unsigned nmono = (ndb & 0x80000000u) ? ~ndb : (ndb | 0x80000000u);
      mykey = ((unsigned long long)nmono << 32) |
              (unsigned int)(nljj * 64 + lane);
    }
  }
  if (lane < 32) knn[center * 32 + lane] = out_p;
}

// ======================= weight transpose =====================
__global__ void prep_kernel(const float* __restrict__ w1, const float* __restrict__ w2,
                            float* __restrict__ w1t, float* __restrict__ w2t) {
  const int t = blockIdx.x * 256 + threadIdx.x;
  if (t < 4096) { const int o = t >> 6, c = t & 63; w1t[c * 64 + o] = w1[t]; }
  if (t < 8192) { const int o = t >> 6, c = t & 63; w2t[c * 128 + o] = w2[t]; }
}

// ===================== layer-1 stats pass =====================
__global__ __launch_bounds__(256) void s1_kernel(const float* __restrict__ xyz,
                                                 const float* __restrict__ dout,
                                                 const int* __restrict__ knn,
                                                 const float* __restrict__ w0,
                                                 const float* __restrict__ b0,
                                                 float* __restrict__ part1) {
  __shared__ float tw[4 * 4096];  // 64 KB transpose buffers (16 KB/wave)
  const int tid = threadIdx.x;
  const int r = blockIdx.x * 256 + tid;
  const int cid = r >> 5;
  const int b = cid >> 10;
  const int m = cid & 1023;
  const int idx = knn[r];
  const float* pp = xyz + ((size_t)b * NN_ + idx) * 3;
  const float* cc = dout + ((size_t)b * MM_ + m) * 3;
  const float fx = pp[0] - cc[0];
  const float fy = pp[1] - cc[1];
  const float fz = pp[2] - cc[2];
  float acc[64];
#pragma unroll
  for (int o = 0; o < 64; ++o)
    acc[o] = fmaf(w0[o * 3 + 2], fz, fmaf(w0[o * 3 + 1], fy, fmaf(w0[o * 3 + 0], fx, b0[o])));
  const int lane = tid & 63;
  const int wv = tid >> 6;
  float* T = &tw[wv * 4096];
  float* po = part1 + ((size_t)blockIdx.x * 4 + wv) * 128;
  WAVE_STATS(T, acc, po, po + 64)
}

// ============ BN-fold reduce: partials -> scale/shift ==========
__global__ __launch_bounds__(256) void rstat_kernel(const float* __restrict__ part, int C,
                                                    const float* __restrict__ g,
                                                    const float* __restrict__ be,
                                                    float* __restrict__ sc,
                                                    float* __restrict__ sh) {
  const int c = blockIdx.x;
  const int tid = threadIdx.x;
  float S = 0.0f, Q = 0.0f;
  for (int i = tid; i < 4096; i += 256) {
    S += part[(size_t)i * 2 * C + c];
    Q += part[(size_t)i * 2 * C + C + c];
  }
  const int lane = tid & 63;
#pragma unroll
  for (int mk = 1; mk < 64; mk <<= 1) { S += __shfl_xor(S, mk, 64); Q += __shfl_xor(Q, mk, 64); }
  __shared__ float rs[4], rq[4];
  if (lane == 0) { rs[tid >> 6] = S; rq[tid >> 6] = Q; }
  __syncthreads();
  if (tid == 0) {
    S = rs[0] + rs[1] + rs[2] + rs[3];
    Q = rq[0] + rq[1] + rq[2] + rq[3];
    const float mean = S * (1.0f / 262144.0f);
    const float var = fmaf(-mean, mean, Q * (1.0f / 262144.0f));
    const float s = g[c] * rsqrtf(var + 1e-5f);
    sc[c] = s;
    sh[c] = fmaf(-mean, s, be[c]);
  }
}

// ============ recompute chain: STAGE 2 = stats2, 3 = stats3, 4 = final ============
// ws-gated a2 caching: if cached!=0, STAGE 2 stores pre-BN conv2 output to
// a2g [64][NROWS] (o-major, coalesced); STAGE 3/4 load it instead of
// recomputing conv1+BN1+conv2 (bit-identical values). Uniform branch.
template <int STAGE>
__global__ __launch_bounds__(256) void chain_kernel(
    const float* __restrict__ xyz, const float* __restrict__ dout,
    const int* __restrict__ knn,
    const float* __restrict__ w0, const float* __restrict__ b0,
    const float* __restrict__ w1t, const float* __restrict__ b1,
    const float* __restrict__ w2t, const float* __restrict__ b2,
    const float* __restrict__ sc1, const float* __restrict__ sh1,
    const float* __restrict__ sc2, const float* __restrict__ sh2,
    const float* __restrict__ sc3, const float* __restrict__ sh3,
    float* __restrict__ part, float* __restrict__ outp,
    float* __restrict__ a2g, int cached) {
  __shared__ float f[64 * 256];  // activations, column layout [c][tid]
  const int tid = threadIdx.x;
  const int r = blockIdx.x * 256 + tid;
  const int cid = r >> 5;
  const int b = cid >> 10;
  const int m = cid & 1023;
  const int lane = tid & 63;
  const int wv = tid >> 6;

  float a2[64];
  if (STAGE == 2 || !cached) {
    const int idx = knn[r];
    const float* pp = xyz + ((size_t)b * NN_ + idx) * 3;
    const float* cc = dout + ((size_t)b * MM_ + m) * 3;
    const float fx = pp[0] - cc[0];
    const float fy = pp[1] - cc[1];
    const float fz = pp[2] - cc[2];
    float acc[64];
#pragma unroll
    for (int o = 0; o < 64; ++o)
      acc[o] = fmaf(w0[o * 3 + 2], fz, fmaf(w0[o * 3 + 1], fy, fmaf(w0[o * 3 + 0], fx, b0[o])));
    // BN1 + ReLU -> own column
#pragma unroll
    for (int o = 0; o < 64; ++o)
      f[o * 256 + tid] = fmaxf(fmaf(acc[o], sc1[o], sh1[o]), 0.0f);
    // conv2 (output-stationary, uniform weight loads, own-column reads)
#pragma unroll
    for (int o = 0; o < 64; ++o) a2[o] = b1[o];
#pragma unroll 4
    for (int c = 0; c < 64; ++c) {
      const float x = f[c * 256 + tid];
#pragma unroll
      for (int o = 0; o < 64; ++o) a2[o] = fmaf(w1t[c * 64 + o], x, a2[o]);
    }
  } else {
    // cached path: reload bit-identical pre-BN conv2 output (coalesced)
#pragma unroll
    for (int o = 0; o < 64; ++o) a2[o] = a2g[(size_t)o * NROWS_ + r];
  }

  if constexpr (STAGE == 2) {
    if (cached) {
#pragma unroll
      for (int o = 0; o < 64; ++o) a2g[(size_t)o * NROWS_ + r] = a2[o];
    }
    __syncthreads();  // all conv2 column-reads done before overwriting f
    float* T = &f[wv * 4096];
    float* po = part + ((size_t)blockIdx.x * 4 + wv) * 128;
    WAVE_STATS(T, a2, po, po + 64)
    return;
  }
  // BN2 + ReLU -> own column
#pragma unroll
  for (int o = 0; o < 64; ++o)
    f[o * 256 + tid] = fmaxf(fmaf(a2[o], sc2[o], sh2[o]), 0.0f);
  if constexpr (STAGE == 3) {
    // fused both-halves conv3, then transpose-stats twice
    float a3l[64], a3h[64];
#pragma unroll
    for (int o = 0; o < 64; ++o) { a3l[o] = b2[o]; a3h[o] = b2[64 + o]; }
#pragma unroll 2
    for (int c = 0; c < 64; ++c) {
      const float x = f[c * 256 + tid];
#pragma unroll
      for (int o = 0; o < 64; ++o) a3l[o] = fmaf(w2t[c * 128 + o], x, a3l[o]);
#pragma unroll
      for (int o = 0; o < 64; ++o) a3h[o] = fmaf(w2t[c * 128 + 64 + o], x, a3h[o]);
    }
    __syncthreads();  // all conv3 column-reads done before overwriting f
    float* T = &f[wv * 4096];
    float* po = part + ((size_t)blockIdx.x * 4 + wv) * 256;
    WAVE_STATS(T, a3l, po, po + 128)
    WAVE_STATS(T, a3h, po + 64, po + 192)
    return;
  }
  // STAGE 4: conv3 + BN3 + ReLU + max over k + transposed store
#pragma unroll
  for (int h = 0; h < 2; ++h) {
    float a3[64];
#pragma unroll
    for (int o = 0; o < 64; ++o) a3[o] = b2[h * 64 + o];
#pragma unroll 4
    for (int c = 0; c < 64; ++c) {
      const float x = f[c * 256 + tid];
#pragma unroll
      for (int o = 0; o < 64; ++o) a3[o] = fmaf(w2t[c * 128 + h * 64 + o], x, a3[o]);
    }
#pragma unroll
    for (int o = 0; o < 64; ++o) {
      float v = fmaxf(fmaf(a3[o], sc3[h * 64 + o], sh3[h * 64 + o]), 0.0f);
#pragma unroll
      for (int mk = 1; mk < 32; mk <<= 1) v = fmaxf(v, __shfl_xor(v, mk, 64));
      if ((lane & 31) == 0)
        outp[24576 + (size_t)b * 131072 + (size_t)(h * 64 + o) * 1024 + m] = v;
    }
  }
}

// ============================ launch =============================
extern "C" void kernel_launch(void* const* d_in, const int* in_sizes, int n_in,
                              void* d_out, int out_size, void* d_ws, size_t ws_size,
                              hipStream_t stream) {
  const float* xyz = (const float*)d_in[0];
  const float* w0 = (const float*)d_in[1];
  const float* b0 = (const float*)d_in[2];
  const float* g0 = (const float*)d_in[3];
  const float* be0 = (const float*)d_in[4];
  const float* w1 = (const float*)d_in[5];
  const float* b1 = (const float*)d_in[6];
  const float* g1 = (const float*)d_in[7];
  const float* be1 = (const float*)d_in[8];
  const float* w2 = (const float*)d_in[9];
  const float* b2 = (const float*)d_in[10];
  const float* g2 = (const float*)d_in[11];
  const float* be2 = (const float*)d_in[12];
  float* out = (float*)d_out;
  char* ws = (char*)d_ws;

  // ws layout: low 16 MB small buffers; a2 cache at +16 MB if available.
  int* knn = (int*)ws;                                   // [8192][32] ints
  float* part1 = (float*)(ws + (size_t)1 * (1 << 20));   // [4096][128]
  float* part2 = (float*)(ws + (size_t)3 * (1 << 20));   // [4096][128]
  float* part3 = (float*)(ws + (size_t)5 * (1 << 20));   // [4096][256]
  float* sc1 = (float*)(ws + (size_t)9 * (1 << 20));
  float* sh1 = sc1 + 64;
  float* sc2 = sh1 + 64;
  float* sh2 = sc2 + 64;
  float* sc3 = sh2 + 64;
  float* sh3 = sc3 + 128;
  float* w1t = sh3 + 128;
  float* w2t = w1t + 4096;
  float* a2g = (float*)(ws + ((size_t)16 << 20));        // [64][262144] = 64 MB
  const int cached = (ws_size >= ((size_t)81 << 20)) ? 1 : 0;

  fps_kernel<<<8, 256, 0, stream>>>(xyz, out);
  knn_kernel<<<8192, 64, 0, stream>>>(xyz, out, knn);
  prep_kernel<<<32, 256, 0, stream>>>(w1, w2, w1t, w2t);
  s1_kernel<<<1024, 256, 0, stream>>>(xyz, out, knn, w0, b0, part1);
  rstat_kernel<<<64, 256, 0, stream>>>(part1, 64, g0, be0, sc1, sh1);
  chain_kernel<2><<<1024, 256, 0, stream>>>(xyz, out, knn, w0, b0, w1t, b1, w2t, b2,
                                            sc1, sh1, sc2, sh2, sc3, sh3, part2, out,
                                            a2g, cached);
  rstat_kernel<<<64, 256, 0, stream>>>(part2, 64, g1, be1, sc2, sh2);
  chain_kernel<3><<<1024, 256, 0, stream>>>(xyz, out, knn, w0, b0, w1t, b1, w2t, b2,
                                            sc1, sh1, sc2, sh2, sc3, sh3, part3, out,
                                            a2g, cached);
  rstat_kernel<<<128, 256, 0, stream>>>(part3, 128, g2, be2, sc3, sh3);
  chain_kernel<4><<<1024, 256, 0, stream>>>(xyz, out, knn, w0, b0, w1t, b1, w2t, b2,
                                            sc1, sh1, sc2, sh2, sc3, sh3, part3, out,
                                            a2g, cached);
}